// Round 4
// baseline (111.050 us; speedup 1.0000x reference)
//
#include <hip/hip_runtime.h>
#include <hip/hip_bf16.h>

// n=2,t=16 -> 32 frames; C=64; HW=4096; M=512; 32 groups (2 ch/group).
#define NFRAME 32
#define CCH 64
#define HW 4096
#define MSLOT 512

typedef __attribute__((ext_vector_type(8))) short s16x8;    // 8 bf16 MFMA A/B frag
typedef __attribute__((ext_vector_type(16))) float f32x16;  // 32x32 MFMA C/D frag
typedef __attribute__((ext_vector_type(4))) unsigned int u32x4;
typedef unsigned short u16;
typedef unsigned int u32;

// f32 workspace offsets
#define WS_STATS 0          // 1024*2 f32
#define WS_OFF   2048       // 32*64 f32
#define WS_BF16  4096       // u16 region starts here (float offset)
// u16 offsets inside bf16 region (fragment-ordered for 32x32x16 MFMA)
#define BW_WFRAW 0                         // [32][64 o][64 c] folded phi weights (raw)
#define BW_KF    131072                    // [16 q][4 ks][64 l][8]   QK^T A-frags (K rows m)
#define BW_VF    163840                    // [16 q][2 mh][2 ct][64 l][8] PV A-frags (V^T rows c)
#define BW_WZF   196608                    // [2 ot][4 ks][64 l][8]   wz A-frags
#define BW_WFF   200704                    // [32 b][2 ot][4 ks][64 l][8] phi A-frags

// exp2-domain scale: 1/sqrt(64) * log2(e)
#define QSCALE 0.18033688011112042f

static __device__ __forceinline__ u16 f2b(float f) {
  __hip_bfloat16 h = __float2bfloat16(f);
  return *reinterpret_cast<u16*>(&h);
}
static __device__ __forceinline__ f32x16 zero16() {
  f32x16 z;
#pragma unroll
  for (int r = 0; r < 16; ++r) z[r] = 0.f;
  return z;
}

// ---------------- kernel 1: GroupNorm stats ----------------
__global__ __launch_bounds__(256) void k_stats(const float* __restrict__ x,
                                               float* __restrict__ ws) {
  const int bg = blockIdx.x;
  const float4* xp = (const float4*)(x + (size_t)bg * 8192);
  const int t = threadIdx.x;
  float s = 0.f, s2 = 0.f;
#pragma unroll
  for (int i = 0; i < 8; ++i) {
    float4 v = xp[t + i * 256];
    s  += v.x + v.y + v.z + v.w;
    s2 += v.x * v.x + v.y * v.y + v.z * v.z + v.w * v.w;
  }
  for (int off = 32; off; off >>= 1) {
    s  += __shfl_down(s,  off, 64);
    s2 += __shfl_down(s2, off, 64);
  }
  __shared__ float ls[8];
  const int wid = t >> 6;
  if ((t & 63) == 0) { ls[wid * 2] = s; ls[wid * 2 + 1] = s2; }
  __syncthreads();
  if (t == 0) {
    float S = 0.f, S2 = 0.f;
#pragma unroll
    for (int w = 0; w < 4; ++w) { S += ls[w * 2]; S2 += ls[w * 2 + 1]; }
    float mean = S * (1.f / 8192.f);
    float var  = S2 * (1.f / 8192.f) - mean * mean;
    float rstd = rsqrtf(var + 1e-6f);
    ws[WS_STATS + bg * 2]     = mean;
    ws[WS_STATS + bg * 2 + 1] = rstd;
  }
}

// ---------------- kernel 2: fold GN + scale into bf16 phi weights ----------------
__global__ __launch_bounds__(64) void k_prep(const float* __restrict__ phi_w,
                                             const float* __restrict__ phi_b,
                                             const float* __restrict__ gamma,
                                             const float* __restrict__ beta,
                                             float* __restrict__ ws) {
  const int b = blockIdx.x;
  const int o = threadIdx.x;
  u16* wf = (u16*)(ws + WS_BF16) + BW_WFRAW + ((size_t)b * 64 + o) * 64;
  float offacc = 0.f;
  for (int c = 0; c < CCH; ++c) {
    const int g = c >> 1;
    const float mean = ws[WS_STATS + (b * 32 + g) * 2];
    const float rstd = ws[WS_STATS + (b * 32 + g) * 2 + 1];
    const float a = gamma[c] * rstd;
    const float d = beta[c] - mean * a;
    const float wv = phi_w[o * 64 + c];
    wf[c] = f2b(wv * a * QSCALE);
    offacc += wv * d;
  }
  ws[WS_OFF + b * 64 + o] = (offacc + phi_b[o]) * QSCALE;
}

// ---------------- kernel 3: build 32x32-fragment-ordered operand tables ----------------
__global__ __launch_bounds__(256) void k_tr(const float* __restrict__ mb,
                                            const float* __restrict__ wz_w,
                                            float* __restrict__ ws) {
  u16* wbw = (u16*)(ws + WS_BF16);
  const int i = blockIdx.x * 256 + threadIdx.x;
  if (i < 32768) {                           // KF[q][ks][l][j]: m=q*32+(l&31), c=ks*16+(l>>5)*8+j
    const int j = i & 7, l = (i >> 3) & 63, ks = (i >> 9) & 3, q = i >> 11;
    const int c = ks * 16 + ((l >> 5) << 3) + j;
    const int m = q * 32 + (l & 31);
    wbw[BW_KF + i] = f2b(mb[c * MSLOT + m]);
  } else if (i < 65536) {                    // VF[q][mh][ct][l][j]: c=ct*32+(l&31), m=q*32+mh*16+(l>>5)*8+j
    const int i2 = i - 32768;
    const int j = i2 & 7, l = (i2 >> 3) & 63, ct = (i2 >> 9) & 1, mh = (i2 >> 10) & 1, q = i2 >> 11;
    const int c = ct * 32 + (l & 31);
    const int m = q * 32 + mh * 16 + ((l >> 5) << 3) + j;
    wbw[BW_VF + i2] = f2b(mb[c * MSLOT + m]);
  } else if (i < 69632) {                    // WZF[ot][ks][l][j]: o=ot*32+(l&31), c=ks*16+(l>>5)*8+j
    const int i3 = i - 65536;
    const int j = i3 & 7, l = (i3 >> 3) & 63, ks = (i3 >> 9) & 3, ot = i3 >> 11;
    const int o = ot * 32 + (l & 31);
    const int c = ks * 16 + ((l >> 5) << 3) + j;
    wbw[BW_WZF + i3] = f2b(wz_w[o * 64 + c]);
  } else {                                   // WFF[b][ot][ks][l][j]
    const int i4 = i - 69632;
    const int j = i4 & 7, l = (i4 >> 3) & 63, ks = (i4 >> 9) & 3, ot = (i4 >> 11) & 1, b = i4 >> 12;
    const int o = ot * 32 + (l & 31);
    const int c = ks * 16 + ((l >> 5) << 3) + j;
    wbw[BW_WFF + i4] = wbw[BW_WFRAW + ((size_t)b * 64 + o) * 64 + c];
  }
}

// ---------------- kernel 4: phi -> no-max m-split attention (permlane P-transpose) -> wz ----------------
// grid: 32 frames * 64 pixel-tiles; 4 waves; wave w owns m in [w*128, +128).
// 32x32x16 layouts: A/B: row|col=lane&31, k=(lane>>5)*8+j. D: col=lane&31, row=(reg&3)+8*(reg>>2)+4*(lane>>5).
__global__ __launch_bounds__(256, 3) void k_main(const float* __restrict__ x,
                                                 const float* __restrict__ ws,
                                                 const float* __restrict__ wz_b,
                                                 float* __restrict__ out) {
  const int b  = blockIdx.x >> 6;
  const int p0 = (blockIdx.x & 63) * 64;
  const int tid  = threadIdx.x;
  const int w    = tid >> 6;
  const int lane = tid & 63;
  const int l5 = lane & 31;
  const int hi = lane >> 5;

  const u16* wb = (const u16*)(ws + WS_BF16);

  // phase-1: xt[64p][64c] u16 swz @0, pht[64p][64o] u16 swz @8192
  // phase-2 overlay: yp u32[4w][32 c2][64 p] @0 (32K), lsum f32[4][64] @32768, yT u16 swz @33792 (8K)
  __shared__ __align__(16) unsigned char lds[41984];
  u32* yp = (u32*)lds;
  float* lsum = (float*)(lds + 32768);

  // ---- stage x tile (bf16, transposed [p][c], 16B-granule XOR swizzle) ----
  {
    const int p = lane;
    const int key = (p & 7) << 4;
    const float* xc = x + (size_t)b * CCH * HW + p0 + p;
#pragma unroll
    for (int j = 0; j < 8; ++j) {
      const int c = w * 16 + j * 2;
      const u32 pk = (u32)f2b(xc[(size_t)c * HW]) | ((u32)f2b(xc[(size_t)(c + 1) * HW]) << 16);
      *(u32*)(lds + p * 128 + ((c * 2) ^ key)) = pk;
    }
  }
  __syncthreads();

  // ---- phase A: phi = Wfold @ x + off ; wave computes quadrant (ot=w&1, pt2=w>>1) ----
  {
    const int ot = w & 1, pt2 = w >> 1;
    const int p = pt2 * 32 + l5;
    const int key = (p & 7) << 4;
    s16x8 a[4];
#pragma unroll
    for (int ks = 0; ks < 4; ++ks)
      a[ks] = *(const s16x8*)(wb + BW_WFF + ((((size_t)b * 2 + ot) * 4 + ks) * 64 + lane) * 8);
    f32x16 acc = zero16();
#pragma unroll
    for (int ks = 0; ks < 4; ++ks) {
      const s16x8 bx = *(const s16x8*)(lds + p * 128 + (((ks * 2 + hi) * 16) ^ key));
      acc = __builtin_amdgcn_mfma_f32_32x32x16_bf16(a[ks], bx, acc, 0, 0, 0);
    }
    const float* offb = ws + WS_OFF + b * 64;
#pragma unroll
    for (int rq = 0; rq < 4; ++rq) {
      const int obase = ot * 32 + rq * 8 + hi * 4;
      const float4 offv = *(const float4*)(offb + obase);
#pragma unroll
      for (int rp = 0; rp < 2; ++rp) {
        const float e0 = acc[rq * 4 + rp * 2]     + ((const float*)&offv)[rp * 2];
        const float e1 = acc[rq * 4 + rp * 2 + 1] + ((const float*)&offv)[rp * 2 + 1];
        const u32 pk = (u32)f2b(e0) | ((u32)f2b(e1) << 16);
        *(u32*)(lds + 8192 + p * 128 + (((obase + rp * 2) * 2) ^ key)) = pk;
      }
    }
  }
  __syncthreads();

  // ---- Q-frags for both p-tiles (loop-invariant registers) ----
  s16x8 q[2][4];
#pragma unroll
  for (int pt = 0; pt < 2; ++pt) {
    const int p = pt * 32 + l5;
    const int key = (p & 7) << 4;
#pragma unroll
    for (int ks = 0; ks < 4; ++ks)
      q[pt][ks] = *(const s16x8*)(lds + 8192 + p * 128 + (((ks * 2 + hi) * 16) ^ key));
  }
  __syncthreads();   // xt/pht dead -> yp overlay may begin

  // ---- m-split attention, NO max subtraction (benign gaussian logits) ----
  f32x16 Y[2][2];    // [ct][pt]
#pragma unroll
  for (int ct = 0; ct < 2; ++ct)
#pragma unroll
    for (int pt = 0; pt < 2; ++pt) Y[ct][pt] = zero16();
  float Lacc[2] = {0.f, 0.f};

#pragma unroll
  for (int sc = 0; sc < 4; ++sc) {
    const int qch = w * 4 + sc;
    s16x8 kf[4], vf[2][2];
#pragma unroll
    for (int ks = 0; ks < 4; ++ks)
      kf[ks] = *(const s16x8*)(wb + BW_KF + (((size_t)qch * 4 + ks) * 64 + lane) * 8);
#pragma unroll
    for (int mh = 0; mh < 2; ++mh)
#pragma unroll
      for (int ct = 0; ct < 2; ++ct)
        vf[mh][ct] = *(const s16x8*)(wb + BW_VF + ((((size_t)qch * 2 + mh) * 2 + ct) * 64 + lane) * 8);

#pragma unroll
    for (int pt = 0; pt < 2; ++pt) {
      f32x16 s = zero16();
#pragma unroll
      for (int ks = 0; ks < 4; ++ks)
        s = __builtin_amdgcn_mfma_f32_32x32x16_bf16(kf[ks], q[pt][ks], s, 0, 0, 0);
      float e[16];
      float ls = 0.f;
#pragma unroll
      for (int r = 0; r < 16; ++r) { e[r] = exp2f(s[r]); ls += e[r]; }
      Lacc[pt] += ls;
      // P-transpose fully in-register: pack pairs + permlane32_swap -> PV B-frags
#pragma unroll
      for (int mh = 0; mh < 2; ++mh) {
        u32 P0 = (u32)f2b(e[mh * 8 + 0]) | ((u32)f2b(e[mh * 8 + 1]) << 16);
        u32 P1 = (u32)f2b(e[mh * 8 + 2]) | ((u32)f2b(e[mh * 8 + 3]) << 16);
        u32 Q0 = (u32)f2b(e[mh * 8 + 4]) | ((u32)f2b(e[mh * 8 + 5]) << 16);
        u32 Q1 = (u32)f2b(e[mh * 8 + 6]) | ((u32)f2b(e[mh * 8 + 7]) << 16);
        asm volatile("v_permlane32_swap_b32 %0, %1" : "+v"(P0), "+v"(Q0));
        asm volatile("v_permlane32_swap_b32 %0, %1" : "+v"(P1), "+v"(Q1));
        u32x4 bw = {P0, P1, Q0, Q1};
        const s16x8 pf = __builtin_bit_cast(s16x8, bw);
#pragma unroll
        for (int ct = 0; ct < 2; ++ct)
          Y[ct][pt] = __builtin_amdgcn_mfma_f32_32x32x16_bf16(vf[mh][ct], pf, Y[ct][pt], 0, 0, 0);
      }
    }
  }

  // ---- publish partials (conflict-free: bank = p mod 32) ----
#pragma unroll
  for (int pt = 0; pt < 2; ++pt) {
    const float l2 = Lacc[pt] + __shfl_xor(Lacc[pt], 32, 64);
    if (hi == 0) lsum[w * 64 + pt * 32 + l5] = l2;
  }
#pragma unroll
  for (int ct = 0; ct < 2; ++ct)
#pragma unroll
    for (int pt = 0; pt < 2; ++pt)
#pragma unroll
      for (int rq = 0; rq < 4; ++rq)
#pragma unroll
        for (int rp = 0; rp < 2; ++rp) {
          const int r = rq * 4 + rp * 2;
          const u32 pk = (u32)f2b(Y[ct][pt][r]) | ((u32)f2b(Y[ct][pt][r + 1]) << 16);
          const int c2 = ct * 16 + hi * 2 + rq * 4 + rp;
          yp[((size_t)w * 32 + c2) * 64 + pt * 32 + l5] = pk;
        }
  __syncthreads();

  // ---- merge: wave w sums c2-range [8w, 8w+8) over 4 m-quarters, scales by 1/L ----
  {
    const int p = lane;
    const float Ltot = lsum[p] + lsum[64 + p] + lsum[128 + p] + lsum[192 + p];
    const float invL = 1.f / Ltot;
    const int key = (p & 7) << 4;
#pragma unroll
    for (int c2i = 0; c2i < 8; ++c2i) {
      const int c2 = w * 8 + c2i;
      float y0 = 0.f, y1 = 0.f;
#pragma unroll
      for (int w2 = 0; w2 < 4; ++w2) {
        const u32 v = yp[((size_t)w2 * 32 + c2) * 64 + p];
        y0 += __builtin_bit_cast(float, v << 16);
        y1 += __builtin_bit_cast(float, v & 0xffff0000u);
      }
      const u32 pk = (u32)f2b(y0 * invL) | ((u32)f2b(y1 * invL) << 16);
      *(u32*)(lds + 33792 + p * 128 + ((c2 * 4) ^ key)) = pk;   // yT[p][c=2*c2]
    }
  }
  __syncthreads();

  // ---- phase D: out = wz @ y + wz_b + x ; wave quadrant (ot, pt2) ----
  {
    const int ot = w & 1, pt2 = w >> 1;
    const int p = pt2 * 32 + l5;
    const int key = (p & 7) << 4;
    s16x8 a[4];
#pragma unroll
    for (int ks = 0; ks < 4; ++ks)
      a[ks] = *(const s16x8*)(wb + BW_WZF + (((size_t)ot * 4 + ks) * 64 + lane) * 8);
    f32x16 acc = zero16();
#pragma unroll
    for (int ks = 0; ks < 4; ++ks) {
      const s16x8 by = *(const s16x8*)(lds + 33792 + p * 128 + (((ks * 2 + hi) * 16) ^ key));
      acc = __builtin_amdgcn_mfma_f32_32x32x16_bf16(a[ks], by, acc, 0, 0, 0);
    }
    const float* xb = x + (size_t)b * CCH * HW + p0;
    float* ob = out + (size_t)b * CCH * HW + p0;
#pragma unroll
    for (int rq = 0; rq < 4; ++rq) {
      const int obase = ot * 32 + rq * 8 + hi * 4;
      const float4 bz = *(const float4*)(wz_b + obase);
#pragma unroll
      for (int rr = 0; rr < 4; ++rr) {
        const size_t idx = (size_t)(obase + rr) * HW + p;
        ob[idx] = acc[rq * 4 + rr] + ((const float*)&bz)[rr] + xb[idx];
      }
    }
  }
}

extern "C" void kernel_launch(void* const* d_in, const int* in_sizes, int n_in,
                              void* d_out, int out_size, void* d_ws, size_t ws_size,
                              hipStream_t stream) {
  const float* x     = (const float*)d_in[0];
  const float* gamma = (const float*)d_in[1];
  const float* beta  = (const float*)d_in[2];
  const float* phi_w = (const float*)d_in[3];
  const float* phi_b = (const float*)d_in[4];
  const float* mb    = (const float*)d_in[5];
  const float* wz_w  = (const float*)d_in[6];
  const float* wz_b  = (const float*)d_in[7];
  float* out = (float*)d_out;
  float* ws  = (float*)d_ws;

  k_stats<<<1024, 256, 0, stream>>>(x, ws);
  k_prep<<<32, 64, 0, stream>>>(phi_w, phi_b, gamma, beta, ws);
  k_tr<<<784, 256, 0, stream>>>(mb, wz_w, ws);
  k_main<<<NFRAME * 64, 256, 0, stream>>>(x, ws, wz_b, out);
}

// Round 6
// 61.747 us; speedup vs baseline: 1.7985x; 1.7985x over previous
//
#include <hip/hip_runtime.h>
#include <hip/hip_bf16.h>

// n=2,t=16 -> 32 frames; C=64; HW=4096; M=512; 32 groups (2 ch/group).
#define NFRAME 32
#define CCH 64
#define HW 4096
#define MSLOT 512

typedef __attribute__((ext_vector_type(8))) short s16x8;    // 8 bf16 MFMA A/B frag
typedef __attribute__((ext_vector_type(16))) float f32x16;  // 32x32 MFMA C/D frag
typedef __attribute__((ext_vector_type(4))) unsigned int u32x4;
typedef __attribute__((ext_vector_type(2))) unsigned int u32x2;
typedef unsigned short u16;
typedef unsigned int u32;

// f32 workspace offsets
#define WS_STATS 0          // 1024*2 f32
#define WS_OFF   2048       // 32*64 f32
#define WS_BF16  4096       // u16 region starts here (float offset)
// u16 offsets inside bf16 region (fragment-ordered for 32x32x16 MFMA)
#define BW_WFRAW 0                         // [32][64 o][64 c] folded phi weights (raw)
#define BW_KF    131072                    // [16 q][4 ks][64 l][8]   QK^T A-frags (K rows m)
#define BW_VF    163840                    // [16 q][2 mh][2 ct][64 l][8] PV A-frags (V^T rows c)
#define BW_WZF   196608                    // [2 ot][4 ks][64 l][8]   wz A-frags
#define BW_WFF   200704                    // [32 b][2 ot][4 ks][64 l][8] phi A-frags

// exp2-domain scale: 1/sqrt(64) * log2(e)
#define QSCALE 0.18033688011112042f

static __device__ __forceinline__ u16 f2b(float f) {
  __hip_bfloat16 h = __float2bfloat16(f);
  return *reinterpret_cast<u16*>(&h);
}
static __device__ __forceinline__ f32x16 zero16() {
  f32x16 z;
#pragma unroll
  for (int r = 0; r < 16; ++r) z[r] = 0.f;
  return z;
}

// ---------------- kernel 1: GroupNorm stats ----------------
__global__ __launch_bounds__(256) void k_stats(const float* __restrict__ x,
                                               float* __restrict__ ws) {
  const int bg = blockIdx.x;
  const float4* xp = (const float4*)(x + (size_t)bg * 8192);
  const int t = threadIdx.x;
  float s = 0.f, s2 = 0.f;
#pragma unroll
  for (int i = 0; i < 8; ++i) {
    float4 v = xp[t + i * 256];
    s  += v.x + v.y + v.z + v.w;
    s2 += v.x * v.x + v.y * v.y + v.z * v.z + v.w * v.w;
  }
  for (int off = 32; off; off >>= 1) {
    s  += __shfl_down(s,  off, 64);
    s2 += __shfl_down(s2, off, 64);
  }
  __shared__ float ls[8];
  const int wid = t >> 6;
  if ((t & 63) == 0) { ls[wid * 2] = s; ls[wid * 2 + 1] = s2; }
  __syncthreads();
  if (t == 0) {
    float S = 0.f, S2 = 0.f;
#pragma unroll
    for (int w = 0; w < 4; ++w) { S += ls[w * 2]; S2 += ls[w * 2 + 1]; }
    float mean = S * (1.f / 8192.f);
    float var  = S2 * (1.f / 8192.f) - mean * mean;
    float rstd = rsqrtf(var + 1e-6f);
    ws[WS_STATS + bg * 2]     = mean;
    ws[WS_STATS + bg * 2 + 1] = rstd;
  }
}

// ---------------- kernel 2: fold GN + scale into bf16 phi weights ----------------
__global__ __launch_bounds__(64) void k_prep(const float* __restrict__ phi_w,
                                             const float* __restrict__ phi_b,
                                             const float* __restrict__ gamma,
                                             const float* __restrict__ beta,
                                             float* __restrict__ ws) {
  const int b = blockIdx.x;
  const int o = threadIdx.x;
  u16* wf = (u16*)(ws + WS_BF16) + BW_WFRAW + ((size_t)b * 64 + o) * 64;
  float offacc = 0.f;
  for (int c = 0; c < CCH; ++c) {
    const int g = c >> 1;
    const float mean = ws[WS_STATS + (b * 32 + g) * 2];
    const float rstd = ws[WS_STATS + (b * 32 + g) * 2 + 1];
    const float a = gamma[c] * rstd;
    const float d = beta[c] - mean * a;
    const float wv = phi_w[o * 64 + c];
    wf[c] = f2b(wv * a * QSCALE);
    offacc += wv * d;
  }
  ws[WS_OFF + b * 64 + o] = (offacc + phi_b[o]) * QSCALE;
}

// ---------------- kernel 3: build 32x32-fragment-ordered operand tables ----------------
__global__ __launch_bounds__(256) void k_tr(const float* __restrict__ mb,
                                            const float* __restrict__ wz_w,
                                            float* __restrict__ ws) {
  u16* wbw = (u16*)(ws + WS_BF16);
  const int i = blockIdx.x * 256 + threadIdx.x;
  if (i < 32768) {                           // KF[q][ks][l][j]: m=q*32+(l&31), c=ks*16+(l>>5)*8+j
    const int j = i & 7, l = (i >> 3) & 63, ks = (i >> 9) & 3, q = i >> 11;
    const int c = ks * 16 + ((l >> 5) << 3) + j;
    const int m = q * 32 + (l & 31);
    wbw[BW_KF + i] = f2b(mb[c * MSLOT + m]);
  } else if (i < 65536) {                    // VF[q][mh][ct][l][j]: c=ct*32+(l&31), m=q*32+mh*16+(l>>5)*8+j
    const int i2 = i - 32768;
    const int j = i2 & 7, l = (i2 >> 3) & 63, ct = (i2 >> 9) & 1, mh = (i2 >> 10) & 1, q = i2 >> 11;
    const int c = ct * 32 + (l & 31);
    const int m = q * 32 + mh * 16 + ((l >> 5) << 3) + j;
    wbw[BW_VF + i2] = f2b(mb[c * MSLOT + m]);
  } else if (i < 69632) {                    // WZF[ot][ks][l][j]: o=ot*32+(l&31), c=ks*16+(l>>5)*8+j
    const int i3 = i - 65536;
    const int j = i3 & 7, l = (i3 >> 3) & 63, ks = (i3 >> 9) & 3, ot = i3 >> 11;
    const int o = ot * 32 + (l & 31);
    const int c = ks * 16 + ((l >> 5) << 3) + j;
    wbw[BW_WZF + i3] = f2b(wz_w[o * 64 + c]);
  } else {                                   // WFF[b][ot][ks][l][j]
    const int i4 = i - 69632;
    const int j = i4 & 7, l = (i4 >> 3) & 63, ks = (i4 >> 9) & 3, ot = (i4 >> 11) & 1, b = i4 >> 12;
    const int o = ot * 32 + (l & 31);
    const int c = ks * 16 + ((l >> 5) << 3) + j;
    wbw[BW_WFF + i4] = wbw[BW_WFRAW + ((size_t)b * 64 + o) * 64 + c];
  }
}

// ---------------- kernel 4: phi -> no-max m-split attention (permlane P-transpose) -> wz ----------------
// grid: 32 frames * 64 pixel-tiles; 4 waves; wave w owns m in [w*128, +128).
// 32x32x16 layouts: A/B: row|col=lane&31, k=(lane>>5)*8+j. D: col=lane&31, row=(reg&3)+8*(reg>>2)+4*(lane>>5).
// r4 post-mortem: (256,3) reg-cap -> scratch spills (WRITE_SIZE 158MB). (256,2) fixes that.
// r5 post-mortem: raw `asm volatile(v_permlane32_swap_b32)` with "+v" is not
// convergent-marked and its cross-lane dataflow is invisible to LLVM; under the
// (256,2) regalloc it miscompiled (absmax 0.836). Use the official builtin,
// which returns the {vdst, vsrc} pair and carries convergent semantics.
__global__ __launch_bounds__(256, 2) void k_main(const float* __restrict__ x,
                                                 const float* __restrict__ ws,
                                                 const float* __restrict__ wz_b,
                                                 float* __restrict__ out) {
  const int b  = blockIdx.x >> 6;
  const int p0 = (blockIdx.x & 63) * 64;
  const int tid  = threadIdx.x;
  const int w    = tid >> 6;
  const int lane = tid & 63;
  const int l5 = lane & 31;
  const int hi = lane >> 5;

  const u16* wb = (const u16*)(ws + WS_BF16);

  // phase-1: xt[64p][64c] u16 swz @0, pht[64p][64o] u16 swz @8192
  // phase-2 overlay: yp u32[4w][32 c2][64 p] @0 (32K), lsum f32[4][64] @32768, yT u16 swz @33792 (8K)
  __shared__ __align__(16) unsigned char lds[41984];
  u32* yp = (u32*)lds;
  float* lsum = (float*)(lds + 32768);

  // ---- stage x tile (bf16, transposed [p][c], 16B-granule XOR swizzle) ----
  {
    const int p = lane;
    const int key = (p & 7) << 4;
    const float* xc = x + (size_t)b * CCH * HW + p0 + p;
#pragma unroll
    for (int j = 0; j < 8; ++j) {
      const int c = w * 16 + j * 2;
      const u32 pk = (u32)f2b(xc[(size_t)c * HW]) | ((u32)f2b(xc[(size_t)(c + 1) * HW]) << 16);
      *(u32*)(lds + p * 128 + ((c * 2) ^ key)) = pk;
    }
  }
  __syncthreads();

  // ---- phase A: phi = Wfold @ x + off ; wave computes quadrant (ot=w&1, pt2=w>>1) ----
  {
    const int ot = w & 1, pt2 = w >> 1;
    const int p = pt2 * 32 + l5;
    const int key = (p & 7) << 4;
    s16x8 a[4];
#pragma unroll
    for (int ks = 0; ks < 4; ++ks)
      a[ks] = *(const s16x8*)(wb + BW_WFF + ((((size_t)b * 2 + ot) * 4 + ks) * 64 + lane) * 8);
    f32x16 acc = zero16();
#pragma unroll
    for (int ks = 0; ks < 4; ++ks) {
      const s16x8 bx = *(const s16x8*)(lds + p * 128 + (((ks * 2 + hi) * 16) ^ key));
      acc = __builtin_amdgcn_mfma_f32_32x32x16_bf16(a[ks], bx, acc, 0, 0, 0);
    }
    const float* offb = ws + WS_OFF + b * 64;
#pragma unroll
    for (int rq = 0; rq < 4; ++rq) {
      const int obase = ot * 32 + rq * 8 + hi * 4;
      const float4 offv = *(const float4*)(offb + obase);
#pragma unroll
      for (int rp = 0; rp < 2; ++rp) {
        const float e0 = acc[rq * 4 + rp * 2]     + ((const float*)&offv)[rp * 2];
        const float e1 = acc[rq * 4 + rp * 2 + 1] + ((const float*)&offv)[rp * 2 + 1];
        const u32 pk = (u32)f2b(e0) | ((u32)f2b(e1) << 16);
        *(u32*)(lds + 8192 + p * 128 + (((obase + rp * 2) * 2) ^ key)) = pk;
      }
    }
  }
  __syncthreads();

  // ---- Q-frags for both p-tiles (loop-invariant registers) ----
  s16x8 q[2][4];
#pragma unroll
  for (int pt = 0; pt < 2; ++pt) {
    const int p = pt * 32 + l5;
    const int key = (p & 7) << 4;
#pragma unroll
    for (int ks = 0; ks < 4; ++ks)
      q[pt][ks] = *(const s16x8*)(lds + 8192 + p * 128 + (((ks * 2 + hi) * 16) ^ key));
  }
  __syncthreads();   // xt/pht dead -> yp overlay may begin

  // ---- m-split attention, NO max subtraction (benign gaussian logits) ----
  f32x16 Y[2][2];    // [ct][pt]
#pragma unroll
  for (int ct = 0; ct < 2; ++ct)
#pragma unroll
    for (int pt = 0; pt < 2; ++pt) Y[ct][pt] = zero16();
  float Lacc[2] = {0.f, 0.f};

#pragma unroll
  for (int sc = 0; sc < 4; ++sc) {
    const int qch = w * 4 + sc;
    s16x8 kf[4], vf[2][2];
#pragma unroll
    for (int ks = 0; ks < 4; ++ks)
      kf[ks] = *(const s16x8*)(wb + BW_KF + (((size_t)qch * 4 + ks) * 64 + lane) * 8);
#pragma unroll
    for (int mh = 0; mh < 2; ++mh)
#pragma unroll
      for (int ct = 0; ct < 2; ++ct)
        vf[mh][ct] = *(const s16x8*)(wb + BW_VF + ((((size_t)qch * 2 + mh) * 2 + ct) * 64 + lane) * 8);

#pragma unroll
    for (int pt = 0; pt < 2; ++pt) {
      f32x16 s = zero16();
#pragma unroll
      for (int ks = 0; ks < 4; ++ks)
        s = __builtin_amdgcn_mfma_f32_32x32x16_bf16(kf[ks], q[pt][ks], s, 0, 0, 0);
      float e[16];
      float ls = 0.f;
#pragma unroll
      for (int r = 0; r < 16; ++r) { e[r] = exp2f(s[r]); ls += e[r]; }
      Lacc[pt] += ls;
      // P-transpose fully in-register: pack pairs + permlane32_swap -> PV B-frags
#pragma unroll
      for (int mh = 0; mh < 2; ++mh) {
        const u32 P0 = (u32)f2b(e[mh * 8 + 0]) | ((u32)f2b(e[mh * 8 + 1]) << 16);
        const u32 P1 = (u32)f2b(e[mh * 8 + 2]) | ((u32)f2b(e[mh * 8 + 3]) << 16);
        const u32 Q0 = (u32)f2b(e[mh * 8 + 4]) | ((u32)f2b(e[mh * 8 + 5]) << 16);
        const u32 Q1 = (u32)f2b(e[mh * 8 + 6]) | ((u32)f2b(e[mh * 8 + 7]) << 16);
        const u32x2 s0 = __builtin_amdgcn_permlane32_swap(P0, Q0, false, false);
        const u32x2 s1 = __builtin_amdgcn_permlane32_swap(P1, Q1, false, false);
        u32x4 bw = {s0[0], s1[0], s0[1], s1[1]};
        const s16x8 pf = __builtin_bit_cast(s16x8, bw);
#pragma unroll
        for (int ct = 0; ct < 2; ++ct)
          Y[ct][pt] = __builtin_amdgcn_mfma_f32_32x32x16_bf16(vf[mh][ct], pf, Y[ct][pt], 0, 0, 0);
      }
    }
  }

  // ---- publish partials (conflict-free: bank = p mod 32) ----
#pragma unroll
  for (int pt = 0; pt < 2; ++pt) {
    const float l2 = Lacc[pt] + __shfl_xor(Lacc[pt], 32, 64);
    if (hi == 0) lsum[w * 64 + pt * 32 + l5] = l2;
  }
#pragma unroll
  for (int ct = 0; ct < 2; ++ct)
#pragma unroll
    for (int pt = 0; pt < 2; ++pt)
#pragma unroll
      for (int rq = 0; rq < 4; ++rq)
#pragma unroll
        for (int rp = 0; rp < 2; ++rp) {
          const int r = rq * 4 + rp * 2;
          const u32 pk = (u32)f2b(Y[ct][pt][r]) | ((u32)f2b(Y[ct][pt][r + 1]) << 16);
          const int c2 = ct * 16 + hi * 2 + rq * 4 + rp;
          yp[((size_t)w * 32 + c2) * 64 + pt * 32 + l5] = pk;
        }
  __syncthreads();

  // ---- merge: wave w sums c2-range [8w, 8w+8) over 4 m-quarters, scales by 1/L ----
  {
    const int p = lane;
    const float Ltot = lsum[p] + lsum[64 + p] + lsum[128 + p] + lsum[192 + p];
    const float invL = 1.f / Ltot;
    const int key = (p & 7) << 4;
#pragma unroll
    for (int c2i = 0; c2i < 8; ++c2i) {
      const int c2 = w * 8 + c2i;
      float y0 = 0.f, y1 = 0.f;
#pragma unroll
      for (int w2 = 0; w2 < 4; ++w2) {
        const u32 v = yp[((size_t)w2 * 32 + c2) * 64 + p];
        y0 += __builtin_bit_cast(float, v << 16);
        y1 += __builtin_bit_cast(float, v & 0xffff0000u);
      }
      const u32 pk = (u32)f2b(y0 * invL) | ((u32)f2b(y1 * invL) << 16);
      *(u32*)(lds + 33792 + p * 128 + ((c2 * 4) ^ key)) = pk;   // yT[p][c=2*c2]
    }
  }
  __syncthreads();

  // ---- phase D: out = wz @ y + wz_b + x ; wave quadrant (ot, pt2) ----
  {
    const int ot = w & 1, pt2 = w >> 1;
    const int p = pt2 * 32 + l5;
    const int key = (p & 7) << 4;
    s16x8 a[4];
#pragma unroll
    for (int ks = 0; ks < 4; ++ks)
      a[ks] = *(const s16x8*)(wb + BW_WZF + (((size_t)ot * 4 + ks) * 64 + lane) * 8);
    f32x16 acc = zero16();
#pragma unroll
    for (int ks = 0; ks < 4; ++ks) {
      const s16x8 by = *(const s16x8*)(lds + 33792 + p * 128 + (((ks * 2 + hi) * 16) ^ key));
      acc = __builtin_amdgcn_mfma_f32_32x32x16_bf16(a[ks], by, acc, 0, 0, 0);
    }
    const float* xb = x + (size_t)b * CCH * HW + p0;
    float* ob = out + (size_t)b * CCH * HW + p0;
#pragma unroll
    for (int rq = 0; rq < 4; ++rq) {
      const int obase = ot * 32 + rq * 8 + hi * 4;
      const float4 bz = *(const float4*)(wz_b + obase);
#pragma unroll
      for (int rr = 0; rr < 4; ++rr) {
        const size_t idx = (size_t)(obase + rr) * HW + p;
        ob[idx] = acc[rq * 4 + rr] + ((const float*)&bz)[rr] + xb[idx];
      }
    }
  }
}

extern "C" void kernel_launch(void* const* d_in, const int* in_sizes, int n_in,
                              void* d_out, int out_size, void* d_ws, size_t ws_size,
                              hipStream_t stream) {
  const float* x     = (const float*)d_in[0];
  const float* gamma = (const float*)d_in[1];
  const float* beta  = (const float*)d_in[2];
  const float* phi_w = (const float*)d_in[3];
  const float* phi_b = (const float*)d_in[4];
  const float* mb    = (const float*)d_in[5];
  const float* wz_w  = (const float*)d_in[6];
  const float* wz_b  = (const float*)d_in[7];
  float* out = (float*)d_out;
  float* ws  = (float*)d_ws;

  k_stats<<<1024, 256, 0, stream>>>(x, ws);
  k_prep<<<32, 64, 0, stream>>>(phi_w, phi_b, gamma, beta, ws);
  k_tr<<<784, 256, 0, stream>>>(mb, wz_w, ws);
  k_main<<<NFRAME * 64, 256, 0, stream>>>(x, ws, wz_b, out);
}

// Round 7
// 61.217 us; speedup vs baseline: 1.8140x; 1.0087x over previous
//
#include <hip/hip_runtime.h>
#include <hip/hip_bf16.h>

// n=2,t=16 -> 32 frames; C=64; HW=4096; M=512; 32 groups (2 ch/group).
#define NFRAME 32
#define CCH 64
#define HW 4096
#define MSLOT 512

typedef __attribute__((ext_vector_type(8))) short s16x8;    // 8 bf16 MFMA A/B frag
typedef __attribute__((ext_vector_type(16))) float f32x16;  // 32x32 MFMA C/D frag
typedef __attribute__((ext_vector_type(4))) unsigned int u32x4;
typedef __attribute__((ext_vector_type(2))) unsigned int u32x2;
typedef unsigned short u16;
typedef unsigned int u32;

// f32 workspace offsets
#define WS_STATS 0          // 1024*2 f32
#define WS_OFF   2048       // 32*64 f32
#define WS_BF16  4096       // u16 region starts here (float offset)
// u16 offsets inside bf16 region (fragment-ordered for 32x32x16 MFMA)
#define BW_KF    0                         // [16 q][4 ks][64 l][8]   QK^T A-frags (K rows m)
#define BW_VF    32768                     // [16 q][2 mh][2 ct][64 l][8] PV A-frags (V^T rows c)
#define BW_WZF   65536                     // [2 ot][4 ks][64 l][8]   wz A-frags
#define BW_WFF   69632                     // [32 b][2 ot][4 ks][64 l][8] phi A-frags

// exp2-domain scale: 1/sqrt(64) * log2(e)
#define QSCALE 0.18033688011112042f

static __device__ __forceinline__ u16 f2b(float f) {
  __hip_bfloat16 h = __float2bfloat16(f);
  return *reinterpret_cast<u16*>(&h);
}
static __device__ __forceinline__ f32x16 zero16() {
  f32x16 z;
#pragma unroll
  for (int r = 0; r < 16; ++r) z[r] = 0.f;
  return z;
}

// ---------------- kernel 1: GroupNorm stats ----------------
__global__ __launch_bounds__(256) void k_stats(const float* __restrict__ x,
                                               float* __restrict__ ws) {
  const int bg = blockIdx.x;
  const float4* xp = (const float4*)(x + (size_t)bg * 8192);
  const int t = threadIdx.x;
  float s = 0.f, s2 = 0.f;
#pragma unroll
  for (int i = 0; i < 8; ++i) {
    float4 v = xp[t + i * 256];
    s  += v.x + v.y + v.z + v.w;
    s2 += v.x * v.x + v.y * v.y + v.z * v.z + v.w * v.w;
  }
  for (int off = 32; off; off >>= 1) {
    s  += __shfl_down(s,  off, 64);
    s2 += __shfl_down(s2, off, 64);
  }
  __shared__ float ls[8];
  const int wid = t >> 6;
  if ((t & 63) == 0) { ls[wid * 2] = s; ls[wid * 2 + 1] = s2; }
  __syncthreads();
  if (t == 0) {
    float S = 0.f, S2 = 0.f;
#pragma unroll
    for (int w = 0; w < 4; ++w) { S += ls[w * 2]; S2 += ls[w * 2 + 1]; }
    float mean = S * (1.f / 8192.f);
    float var  = S2 * (1.f / 8192.f) - mean * mean;
    float rstd = rsqrtf(var + 1e-6f);
    ws[WS_STATS + bg * 2]     = mean;
    ws[WS_STATS + bg * 2 + 1] = rstd;
  }
}

// ---------------- kernel 2: fold GN + scale into bf16 phi weights, emit frag-ordered WFF ----------------
// 32 blocks (one per frame) x 256 threads; weights staged in LDS, written fragment-ordered.
__global__ __launch_bounds__(256) void k_prep(const float* __restrict__ phi_w,
                                              const float* __restrict__ phi_b,
                                              const float* __restrict__ gamma,
                                              const float* __restrict__ beta,
                                              float* __restrict__ ws) {
  const int b = blockIdx.x;
  const int o = threadIdx.x & 63;
  const int quad = threadIdx.x >> 6;
  __shared__ u16 wrow[64 * 64];
  __shared__ float offp[256];
  float offacc = 0.f;
#pragma unroll
  for (int ci = 0; ci < 16; ++ci) {
    const int c = quad * 16 + ci;
    const int g = c >> 1;
    const float mean = ws[WS_STATS + (b * 32 + g) * 2];
    const float rstd = ws[WS_STATS + (b * 32 + g) * 2 + 1];
    const float a = gamma[c] * rstd;
    const float d = beta[c] - mean * a;
    const float wv = phi_w[o * 64 + c];
    wrow[o * 64 + c] = f2b(wv * a * QSCALE);
    offacc += wv * d;
  }
  offp[threadIdx.x] = offacc;
  __syncthreads();
  if (quad == 0) {
    const float off = offp[o] + offp[64 + o] + offp[128 + o] + offp[192 + o];
    ws[WS_OFF + b * 64 + o] = (off + phi_b[o]) * QSCALE;
  }
  u16* wff = (u16*)(ws + WS_BF16) + BW_WFF + (size_t)b * 4096;
#pragma unroll
  for (int k = 0; k < 16; ++k) {
    const int il = threadIdx.x * 16 + k;      // [ot][ks][l][j]
    const int j = il & 7, l = (il >> 3) & 63, ks = (il >> 9) & 3, ot = il >> 11;
    const int oo = ot * 32 + (l & 31);
    const int c = ks * 16 + ((l >> 5) << 3) + j;
    wff[il] = wrow[oo * 64 + c];
  }
}

// ---------------- kernel 3: mb/wz fragment tables (no deps on stats/prep) ----------------
__global__ __launch_bounds__(256) void k_tr(const float* __restrict__ mb,
                                            const float* __restrict__ wz_w,
                                            float* __restrict__ ws) {
  u16* wbw = (u16*)(ws + WS_BF16);
  const int i = blockIdx.x * 256 + threadIdx.x;
  if (i < 32768) {                           // KF[q][ks][l][j]: m=q*32+(l&31), c=ks*16+(l>>5)*8+j
    const int j = i & 7, l = (i >> 3) & 63, ks = (i >> 9) & 3, q = i >> 11;
    const int c = ks * 16 + ((l >> 5) << 3) + j;
    const int m = q * 32 + (l & 31);
    wbw[BW_KF + i] = f2b(mb[c * MSLOT + m]);
  } else if (i < 65536) {                    // VF[q][mh][ct][l][j]: c=ct*32+(l&31), m=q*32+mh*16+(l>>5)*8+j
    const int i2 = i - 32768;
    const int j = i2 & 7, l = (i2 >> 3) & 63, ct = (i2 >> 9) & 1, mh = (i2 >> 10) & 1, q = i2 >> 11;
    const int c = ct * 32 + (l & 31);
    const int m = q * 32 + mh * 16 + ((l >> 5) << 3) + j;
    wbw[BW_VF + i2] = f2b(mb[c * MSLOT + m]);
  } else {                                   // WZF[ot][ks][l][j]: o=ot*32+(l&31), c=ks*16+(l>>5)*8+j
    const int i3 = i - 65536;
    const int j = i3 & 7, l = (i3 >> 3) & 63, ks = (i3 >> 9) & 3, ot = i3 >> 11;
    const int o = ot * 32 + (l & 31);
    const int c = ks * 16 + ((l >> 5) << 3) + j;
    wbw[BW_WZF + i3] = f2b(wz_w[o * 64 + c]);
  }
}

// ---------------- kernel 4: phi -> no-max m-split attention (permlane P-transpose) -> wz ----------------
// grid: 32 frames * 64 pixel-tiles; 4 waves; wave w owns m in [w*128, +128).
// 32x32x16 layouts: A/B: row|col=lane&31, k=(lane>>5)*8+j. D: col=lane&31, row=(reg&3)+8*(reg>>2)+4*(lane>>5).
// r4: (256,3) reg-cap -> scratch spills. (256,2): compiler lands at 128 VGPR, no spill.
// r5: raw asm permlane32_swap miscompiles (not convergent-marked); builtin is correct.
// r6->r7: LDS 41984->33792 (yT written into dead yp region after an extra barrier)
// so 4 blocks/CU fit (163840/33792=4.8) instead of 3; occupancy was the limiter.
__global__ __launch_bounds__(256, 2) void k_main(const float* __restrict__ x,
                                                 const float* __restrict__ ws,
                                                 const float* __restrict__ wz_b,
                                                 float* __restrict__ out) {
  const int b  = blockIdx.x >> 6;
  const int p0 = (blockIdx.x & 63) * 64;
  const int tid  = threadIdx.x;
  const int w    = tid >> 6;
  const int lane = tid & 63;
  const int l5 = lane & 31;
  const int hi = lane >> 5;

  const u16* wb = (const u16*)(ws + WS_BF16);

  // phase-1: xt[64p][64c] u16 swz @0 (8K), pht[64p][64o] u16 swz @8192 (8K)
  // phase-2 overlay: yp u32[4w][32 c2][64 p] @0 (32K), lsum f32[4][64] @32768 (1K)
  // phase-3 overlay: yT[64p][64c] u16 swz @0 (8K, written after merge barrier)
  __shared__ __align__(16) unsigned char lds[33792];
  u32* yp = (u32*)lds;
  float* lsum = (float*)(lds + 32768);

  // ---- stage x tile (bf16, transposed [p][c], 16B-granule XOR swizzle) ----
  {
    const int p = lane;
    const int key = (p & 7) << 4;
    const float* xc = x + (size_t)b * CCH * HW + p0 + p;
#pragma unroll
    for (int j = 0; j < 8; ++j) {
      const int c = w * 16 + j * 2;
      const u32 pk = (u32)f2b(xc[(size_t)c * HW]) | ((u32)f2b(xc[(size_t)(c + 1) * HW]) << 16);
      *(u32*)(lds + p * 128 + ((c * 2) ^ key)) = pk;
    }
  }
  __syncthreads();

  // ---- phase A: phi = Wfold @ x + off ; wave computes quadrant (ot=w&1, pt2=w>>1) ----
  {
    const int ot = w & 1, pt2 = w >> 1;
    const int p = pt2 * 32 + l5;
    const int key = (p & 7) << 4;
    s16x8 a[4];
#pragma unroll
    for (int ks = 0; ks < 4; ++ks)
      a[ks] = *(const s16x8*)(wb + BW_WFF + ((((size_t)b * 2 + ot) * 4 + ks) * 64 + lane) * 8);
    f32x16 acc = zero16();
#pragma unroll
    for (int ks = 0; ks < 4; ++ks) {
      const s16x8 bx = *(const s16x8*)(lds + p * 128 + (((ks * 2 + hi) * 16) ^ key));
      acc = __builtin_amdgcn_mfma_f32_32x32x16_bf16(a[ks], bx, acc, 0, 0, 0);
    }
    const float* offb = ws + WS_OFF + b * 64;
#pragma unroll
    for (int rq = 0; rq < 4; ++rq) {
      const int obase = ot * 32 + rq * 8 + hi * 4;
      const float4 offv = *(const float4*)(offb + obase);
#pragma unroll
      for (int rp = 0; rp < 2; ++rp) {
        const float e0 = acc[rq * 4 + rp * 2]     + ((const float*)&offv)[rp * 2];
        const float e1 = acc[rq * 4 + rp * 2 + 1] + ((const float*)&offv)[rp * 2 + 1];
        const u32 pk = (u32)f2b(e0) | ((u32)f2b(e1) << 16);
        *(u32*)(lds + 8192 + p * 128 + (((obase + rp * 2) * 2) ^ key)) = pk;
      }
    }
  }
  __syncthreads();

  // ---- Q-frags for both p-tiles (loop-invariant registers) ----
  s16x8 q[2][4];
#pragma unroll
  for (int pt = 0; pt < 2; ++pt) {
    const int p = pt * 32 + l5;
    const int key = (p & 7) << 4;
#pragma unroll
    for (int ks = 0; ks < 4; ++ks)
      q[pt][ks] = *(const s16x8*)(lds + 8192 + p * 128 + (((ks * 2 + hi) * 16) ^ key));
  }
  __syncthreads();   // xt/pht dead -> yp overlay may begin

  // ---- m-split attention, NO max subtraction (benign gaussian logits) ----
  f32x16 Y[2][2];    // [ct][pt]
#pragma unroll
  for (int ct = 0; ct < 2; ++ct)
#pragma unroll
    for (int pt = 0; pt < 2; ++pt) Y[ct][pt] = zero16();
  float Lacc[2] = {0.f, 0.f};

#pragma unroll
  for (int sc = 0; sc < 4; ++sc) {
    const int qch = w * 4 + sc;
    s16x8 kf[4], vf[2][2];
#pragma unroll
    for (int ks = 0; ks < 4; ++ks)
      kf[ks] = *(const s16x8*)(wb + BW_KF + (((size_t)qch * 4 + ks) * 64 + lane) * 8);
#pragma unroll
    for (int mh = 0; mh < 2; ++mh)
#pragma unroll
      for (int ct = 0; ct < 2; ++ct)
        vf[mh][ct] = *(const s16x8*)(wb + BW_VF + ((((size_t)qch * 2 + mh) * 2 + ct) * 64 + lane) * 8);

#pragma unroll
    for (int pt = 0; pt < 2; ++pt) {
      f32x16 s = zero16();
#pragma unroll
      for (int ks = 0; ks < 4; ++ks)
        s = __builtin_amdgcn_mfma_f32_32x32x16_bf16(kf[ks], q[pt][ks], s, 0, 0, 0);
      float e[16];
      float ls = 0.f;
#pragma unroll
      for (int r = 0; r < 16; ++r) { e[r] = exp2f(s[r]); ls += e[r]; }
      Lacc[pt] += ls;
      // P-transpose fully in-register: pack pairs + permlane32_swap -> PV B-frags
#pragma unroll
      for (int mh = 0; mh < 2; ++mh) {
        const u32 P0 = (u32)f2b(e[mh * 8 + 0]) | ((u32)f2b(e[mh * 8 + 1]) << 16);
        const u32 P1 = (u32)f2b(e[mh * 8 + 2]) | ((u32)f2b(e[mh * 8 + 3]) << 16);
        const u32 Q0 = (u32)f2b(e[mh * 8 + 4]) | ((u32)f2b(e[mh * 8 + 5]) << 16);
        const u32 Q1 = (u32)f2b(e[mh * 8 + 6]) | ((u32)f2b(e[mh * 8 + 7]) << 16);
        const u32x2 s0 = __builtin_amdgcn_permlane32_swap(P0, Q0, false, false);
        const u32x2 s1 = __builtin_amdgcn_permlane32_swap(P1, Q1, false, false);
        u32x4 bw = {s0[0], s1[0], s0[1], s1[1]};
        const s16x8 pf = __builtin_bit_cast(s16x8, bw);
#pragma unroll
        for (int ct = 0; ct < 2; ++ct)
          Y[ct][pt] = __builtin_amdgcn_mfma_f32_32x32x16_bf16(vf[mh][ct], pf, Y[ct][pt], 0, 0, 0);
      }
    }
  }

  // ---- publish partials (conflict-free: bank = p mod 32) ----
#pragma unroll
  for (int pt = 0; pt < 2; ++pt) {
    const float l2 = Lacc[pt] + __shfl_xor(Lacc[pt], 32, 64);
    if (hi == 0) lsum[w * 64 + pt * 32 + l5] = l2;
  }
#pragma unroll
  for (int ct = 0; ct < 2; ++ct)
#pragma unroll
    for (int pt = 0; pt < 2; ++pt)
#pragma unroll
      for (int rq = 0; rq < 4; ++rq)
#pragma unroll
        for (int rp = 0; rp < 2; ++rp) {
          const int r = rq * 4 + rp * 2;
          const u32 pk = (u32)f2b(Y[ct][pt][r]) | ((u32)f2b(Y[ct][pt][r + 1]) << 16);
          const int c2 = ct * 16 + hi * 2 + rq * 4 + rp;
          yp[((size_t)w * 32 + c2) * 64 + pt * 32 + l5] = pk;
        }
  __syncthreads();

  // ---- merge: wave w sums c2-range [8w, 8w+8) over 4 m-quarters into REGISTERS ----
  u32 ypk[8];
  {
    const int p = lane;
    const float Ltot = lsum[p] + lsum[64 + p] + lsum[128 + p] + lsum[192 + p];
    const float invL = 1.f / Ltot;
#pragma unroll
    for (int c2i = 0; c2i < 8; ++c2i) {
      const int c2 = w * 8 + c2i;
      float y0 = 0.f, y1 = 0.f;
#pragma unroll
      for (int w2 = 0; w2 < 4; ++w2) {
        const u32 v = yp[((size_t)w2 * 32 + c2) * 64 + p];
        y0 += __builtin_bit_cast(float, v << 16);
        y1 += __builtin_bit_cast(float, v & 0xffff0000u);
      }
      ypk[c2i] = (u32)f2b(y0 * invL) | ((u32)f2b(y1 * invL) << 16);
    }
  }
  __syncthreads();   // all yp reads done -> safe to overlay yT @0

  // ---- write yT[p][c] (swizzled) into first 8KB ----
  {
    const int p = lane;
    const int key = (p & 7) << 4;
#pragma unroll
    for (int c2i = 0; c2i < 8; ++c2i) {
      const int c2 = w * 8 + c2i;
      *(u32*)(lds + p * 128 + ((c2 * 4) ^ key)) = ypk[c2i];
    }
  }
  __syncthreads();

  // ---- phase D: out = wz @ y + wz_b + x ; wave quadrant (ot, pt2) ----
  {
    const int ot = w & 1, pt2 = w >> 1;
    const int p = pt2 * 32 + l5;
    const int key = (p & 7) << 4;
    s16x8 a[4];
#pragma unroll
    for (int ks = 0; ks < 4; ++ks)
      a[ks] = *(const s16x8*)(wb + BW_WZF + (((size_t)ot * 4 + ks) * 64 + lane) * 8);
    f32x16 acc = zero16();
#pragma unroll
    for (int ks = 0; ks < 4; ++ks) {
      const s16x8 by = *(const s16x8*)(lds + p * 128 + (((ks * 2 + hi) * 16) ^ key));
      acc = __builtin_amdgcn_mfma_f32_32x32x16_bf16(a[ks], by, acc, 0, 0, 0);
    }
    const float* xb = x + (size_t)b * CCH * HW + p0;
    float* ob = out + (size_t)b * CCH * HW + p0;
#pragma unroll
    for (int rq = 0; rq < 4; ++rq) {
      const int obase = ot * 32 + rq * 8 + hi * 4;
      const float4 bz = *(const float4*)(wz_b + obase);
#pragma unroll
      for (int rr = 0; rr < 4; ++rr) {
        const size_t idx = (size_t)(obase + rr) * HW + p;
        ob[idx] = acc[rq * 4 + rr] + ((const float*)&bz)[rr] + xb[idx];
      }
    }
  }
}

extern "C" void kernel_launch(void* const* d_in, const int* in_sizes, int n_in,
                              void* d_out, int out_size, void* d_ws, size_t ws_size,
                              hipStream_t stream) {
  const float* x     = (const float*)d_in[0];
  const float* gamma = (const float*)d_in[1];
  const float* beta  = (const float*)d_in[2];
  const float* phi_w = (const float*)d_in[3];
  const float* phi_b = (const float*)d_in[4];
  const float* mb    = (const float*)d_in[5];
  const float* wz_w  = (const float*)d_in[6];
  const float* wz_b  = (const float*)d_in[7];
  float* out = (float*)d_out;
  float* ws  = (float*)d_ws;

  k_tr<<<272, 256, 0, stream>>>(mb, wz_w, ws);
  k_stats<<<1024, 256, 0, stream>>>(x, ws);
  k_prep<<<32, 256, 0, stream>>>(phi_w, phi_b, gamma, beta, ws);
  k_main<<<NFRAME * 64, 256, 0, stream>>>(x, ws, wz_b, out);
}